// Round 20
// baseline (83.760 us; speedup 1.0000x reference)
//
#include <hip/hip_runtime.h>
#include <hip/hip_bf16.h>

#define NN 96
// tanh(x) = 1 - 2/(exp2(C*x)+1), C = 2*log2(e)
#define C_TANH 2.8853900817779268f

typedef __attribute__((ext_vector_type(4))) float        f32x4;
typedef __attribute__((ext_vector_type(8))) short        short8;
typedef __attribute__((ext_vector_type(8))) _Float16     half8;
typedef __attribute__((ext_vector_type(4))) unsigned int u32x4;

static __device__ inline unsigned int cvt_pk_bf16(float lo, float hi) {
    unsigned int r;
    asm("v_cvt_pk_bf16_f32 %0, %1, %2" : "=v"(r) : "v"(lo), "v"(hi));
    return r;
}

// L1-bypass (sc0) 16B load: reads the XCD-local L2 directly (dirty lines ok).
static __device__ inline u32x4 load_b128_glc(const void* p) {
    u32x4 d;
    asm volatile("global_load_dwordx4 %0, %1, off sc0"
                 : "=v"(d) : "v"((unsigned long long)p) : "memory");
    return d;
}

// ===========================================================================
// Fused producer-consumer, v2 (R19 proved the sync; this restores occupancy).
// 768 blocks x 256 thr = EXACTLY 3 blocks/CU everywhere (96/XCD); LDS 40KB,
// launch_bounds(256,3) -> co-resident; per-XCD flag cnt[xcd]==96.
// Coherence: all blocks of an XCD meet in that XCD's L2 (bid&7 mapping,
// empirically confirmed by R19 passing): plain stores -> dirty L2;
// vmcnt(0)+barrier -> relaxed add; consumers poll relaxed + read sc0.
// Zero cache-maintenance ops.
//  Producer (= R8's proven gemm): 64M x 64N tile, mb=(xcd*6+sub%6)*64,
//    nb=(sub/6)*64; T14 RA/RB pipeline; Ea=fp16(2^(C*Ha)), Eh=fp16(2^(C*(Hb+b1))).
//  Consumer: 16i x 24j tile of batch b=4*xcd+sub/24; 4 waves = split-k;
//    lane = 2i x 3j; pair-rcp FPROC; out = S - 2*sum(w2/(Ea*Eh+1)).
// ===========================================================================
__global__ __launch_bounds__(256, 3) void fused_pc(
        const float* __restrict__ X, const float* __restrict__ W1,
        const float* __restrict__ b1, const float* __restrict__ w2,
        const float* __restrict__ b2, _Float16* __restrict__ Ea,
        _Float16* __restrict__ Eh, int* __restrict__ cnt,
        float* __restrict__ out) {
    __shared__ __align__(16) char smem[40960];

    int bid = blockIdx.x;                // 768 = 8 xcd * 96
    int tid = threadIdx.x;
    int xcd = bid & 7;
    int sub = bid >> 3;                  // 0..95
    int w   = tid >> 6;
    int l   = tid & 63;

    // ---------------- producer: R8 gemm 64x64 ----------------
    {
        unsigned short* As0 = (unsigned short*)smem;          // [2][2048]
        unsigned short* Bs0 = (unsigned short*)(smem + 8192); // [2][2048]

        int mloc = sub % 6;
        int nq   = sub / 6;              // 0..15
        int mb   = (xcd * 6 + mloc) * 64;
        int nb   = nq * 64;

        int srow = tid >> 2;
        int sg   = (tid & 3) * 8;
        int scs  = sg ^ ((srow & 3) << 3);
        const float* asrc = X + (mb + srow) * 512 + sg;
        int nrow = nb + srow;
        const float* bsrc = W1 + (nrow & 511) * 1024 + ((nrow >> 9) << 9) + sg;
        unsigned short* adst = As0 + srow * 32 + scs;
        unsigned short* bdst = Bs0 + srow * 32 + scs;

        struct Regs { f32x4 a0, a1, b0, b4; };
        Regs RA, RB;

#define LOADR(R, k0)                                                          \
        {                                                                     \
            R.a0 = *(const f32x4*)(asrc + (k0));                              \
            R.a1 = *(const f32x4*)(asrc + (k0) + 4);                          \
            R.b0 = *(const f32x4*)(bsrc + (k0));                              \
            R.b4 = *(const f32x4*)(bsrc + (k0) + 4);                          \
        }
#define WRITER(R, buf)                                                        \
        {                                                                     \
            u32x4 ua, ub;                                                     \
            ua.x = cvt_pk_bf16(R.a0[0], R.a0[1]); ua.y = cvt_pk_bf16(R.a0[2], R.a0[3]); \
            ua.z = cvt_pk_bf16(R.a1[0], R.a1[1]); ua.w = cvt_pk_bf16(R.a1[2], R.a1[3]); \
            ub.x = cvt_pk_bf16(R.b0[0], R.b0[1]); ub.y = cvt_pk_bf16(R.b0[2], R.b0[3]); \
            ub.z = cvt_pk_bf16(R.b4[0], R.b4[1]); ub.w = cvt_pk_bf16(R.b4[2], R.b4[3]); \
            *(u32x4*)(adst + (buf) * 2048) = ua;                              \
            *(u32x4*)(bdst + (buf) * 2048) = ub;                              \
        }

        int lr    = l & 15;
        int koffs = ((l >> 4) * 8) ^ ((lr & 3) << 3);
        int aoff  = (16 * w + lr) * 32 + koffs;
        int boff0 = lr * 32 + koffs;

        f32x4 acc[4] = {};

#define COMPUTE(cur)                                                          \
        {                                                                     \
            short8 afr = *(const short8*)(&As0[(cur) * 2048 + aoff]);         \
            short8 bfr[4];                                                    \
            _Pragma("unroll")                                                 \
            for (int t = 0; t < 4; ++t)                                       \
                bfr[t] = *(const short8*)(&Bs0[(cur) * 2048 + boff0 + t * 512]); \
            _Pragma("unroll")                                                 \
            for (int t = 0; t < 4; ++t)                                       \
                acc[t] = __builtin_amdgcn_mfma_f32_16x16x32_bf16(afr, bfr[t], \
                                                                 acc[t], 0, 0, 0); \
        }

        LOADR(RA, 0)
        WRITER(RA, 0)
        LOADR(RB, 32)
        __syncthreads();
#pragma unroll 1
        for (int kk = 0; kk < 7; ++kk) {
            LOADR(RA, (2 * kk + 2) * 32)
            COMPUTE(0)
            WRITER(RB, 1)
            __syncthreads();
            LOADR(RB, (2 * kk + 3) * 32)
            COMPUTE(1)
            WRITER(RA, 0)
            __syncthreads();
        }
        COMPUTE(0)
        WRITER(RB, 1)
        __syncthreads();
        COMPUTE(1)
#undef LOADR
#undef WRITER
#undef COMPUTE

        // epilogue (plain stores -> dirty same-XCD L2):
        int r0 = (l >> 4) * 4;
        bool isB = (nb >= 512);
        int colbase = nb & 511;
        _Float16* dst = isB ? Eh : Ea;
#pragma unroll
        for (int t = 0; t < 4; ++t) {
            int col = colbase + 16 * t + lr;
            float bias = isB ? b1[col] : 0.0f;
#pragma unroll
            for (int q = 0; q < 4; ++q) {
                int m = mb + 16 * w + r0 + q;
                float arg = (acc[t][q] + bias) * C_TANH;
                dst[m * 512 + col] = (_Float16)exp2f(arg);
            }
        }
    }

    // release at the XCD L2: drain stores, barrier, relaxed add
    asm volatile("s_waitcnt vmcnt(0)" ::: "memory");
    __syncthreads();
    if (tid == 0)
        __hip_atomic_fetch_add(&cnt[xcd], 1, __ATOMIC_RELAXED,
                               __HIP_MEMORY_SCOPE_AGENT);

    // spin (relaxed polls, bounded guard -> absmax fail instead of hang)
    if (tid == 0) {
        int guard = 1 << 22;
        while (--guard &&
               __hip_atomic_load(&cnt[xcd], __ATOMIC_RELAXED,
                                 __HIP_MEMORY_SCOPE_AGENT) < 96)
            __builtin_amdgcn_s_sleep(8);
    }
    __syncthreads();
    asm volatile("" ::: "memory");

    // ---------------- consumer: arc 16i x 24j ----------------
    {
        _Float16* a_s = (_Float16*)smem;                 // 16x512 = 16KB
        _Float16* h_s = (_Float16*)(smem + 16384);       // 24x512 = 24KB

        int b   = 4 * xcd + sub / 24;    // batch, same XCD as its producers
        int rem = sub % 24;
        int it  = rem >> 2;              // 0..5
        int jt  = rem & 3;               // 0..3

        const _Float16* asrc = Ea + (b * NN + it * 16) * 512;
        const _Float16* hsrc = Eh + (b * NN + jt * 24) * 512;

        // stage: a 16x64=1024 chunks (4/thr), h 24x64=1536 (6/thr), sc0.
        u32x4 ra[4], rh[6];
#pragma unroll
        for (int p = 0; p < 4; ++p) {
            int idx = tid + p * 256;
            int row = idx >> 6, c = idx & 63;
            ra[p] = load_b128_glc(asrc + row * 512 + c * 8);
        }
#pragma unroll
        for (int p = 0; p < 6; ++p) {
            int idx = tid + p * 256;
            int row = idx >> 6, c = idx & 63;
            rh[p] = load_b128_glc(hsrc + row * 512 + c * 8);
        }
        asm volatile("s_waitcnt vmcnt(0)" ::: "memory");
#pragma unroll
        for (int p = 0; p < 4; ++p) {
            int idx = tid + p * 256;
            int row = idx >> 6, c = idx & 63, cs = c ^ (row & 7);
            *(u32x4*)(a_s + row * 512 + cs * 8) = ra[p];
        }
#pragma unroll
        for (int p = 0; p < 6; ++p) {
            int idx = tid + p * 256;
            int row = idx >> 6, c = idx & 63, cs = c ^ (row & 7);
            *(u32x4*)(h_s + row * 512 + cs * 8) = rh[p];
        }
        __syncthreads();

        int kq = __builtin_amdgcn_readfirstlane(w);   // SGPR 0..3
        int pi = l >> 3;                 // rows 2pi, 2pi+1
        int pj = l & 7;                  // cols 3pj..3pj+2
        const float* wp = w2 + kq * 128; // uniform -> s_load

        const _Float16* pa[2];
        const _Float16* ph[3];
        int sa[2], sh[3];
#pragma unroll
        for (int d = 0; d < 2; ++d) {
            int r2 = 2 * pi + d;
            pa[d] = a_s + r2 * 512 + kq * 128;
            sa[d] = r2 & 7;
        }
#pragma unroll
        for (int d = 0; d < 3; ++d) {
            int r2 = 3 * pj + d;
            ph[d] = h_s + r2 * 512 + kq * 128;
            sh[d] = r2 & 7;
        }

        float acc[2][3] = {};

#define FPROC(av, hv, a)                                                      \
        {                                                                     \
            float s0 = __builtin_fmaf((float)av[0], (float)hv[0], 1.0f);      \
            float s1 = __builtin_fmaf((float)av[1], (float)hv[1], 1.0f);      \
            float s2 = __builtin_fmaf((float)av[2], (float)hv[2], 1.0f);      \
            float s3 = __builtin_fmaf((float)av[3], (float)hv[3], 1.0f);      \
            float s4 = __builtin_fmaf((float)av[4], (float)hv[4], 1.0f);      \
            float s5 = __builtin_fmaf((float)av[5], (float)hv[5], 1.0f);      \
            float s6 = __builtin_fmaf((float)av[6], (float)hv[6], 1.0f);      \
            float s7 = __builtin_fmaf((float)av[7], (float)hv[7], 1.0f);      \
            float n0 = __builtin_fmaf(wv1, s0, wv0 * s1);                     \
            float n1 = __builtin_fmaf(wv3, s2, wv2 * s3);                     \
            float n2 = __builtin_fmaf(wv5, s4, wv4 * s5);                     \
            float n3 = __builtin_fmaf(wv7, s6, wv6 * s7);                     \
            a = __builtin_fmaf(n0, __builtin_amdgcn_rcpf(s0 * s1), a);        \
            a = __builtin_fmaf(n1, __builtin_amdgcn_rcpf(s2 * s3), a);        \
            a = __builtin_fmaf(n2, __builtin_amdgcn_rcpf(s4 * s5), a);        \
            a = __builtin_fmaf(n3, __builtin_amdgcn_rcpf(s6 * s7), a);        \
        }

#pragma unroll 2
        for (int c0 = 0; c0 < 16; ++c0) {
            half8 av[2], hv[3];
#pragma unroll
            for (int d = 0; d < 2; ++d)
                av[d] = *(const half8*)(pa[d] + ((c0 ^ sa[d]) << 3));
#pragma unroll
            for (int d = 0; d < 3; ++d)
                hv[d] = *(const half8*)(ph[d] + ((c0 ^ sh[d]) << 3));
            f32x4 wlo = *(const f32x4*)(wp + c0 * 8);
            f32x4 whi = *(const f32x4*)(wp + c0 * 8 + 4);
            float wv0 = wlo[0], wv1 = wlo[1], wv2 = wlo[2], wv3 = wlo[3];
            float wv4 = whi[0], wv5 = whi[1], wv6 = whi[2], wv7 = whi[3];
#pragma unroll
            for (int di = 0; di < 2; ++di)
#pragma unroll
                for (int dj = 0; dj < 3; ++dj)
                    FPROC(av[di], hv[dj], acc[di][dj])
        }
#undef FPROC

        // cross-wave reduce; red aliases a_s (post-barrier)
        float* red = (float*)smem;       // [3][64][6] = 4608 B
        __syncthreads();
        if (w != 0) {
            float* rp = red + ((w - 1) * 64 + l) * 6;
#pragma unroll
            for (int di = 0; di < 2; ++di)
#pragma unroll
                for (int dj = 0; dj < 3; ++dj)
                    rp[di * 3 + dj] = acc[di][dj];
        }
        __syncthreads();

        if (w == 0) {
#pragma unroll
            for (int rr = 0; rr < 3; ++rr) {
                const float* rp = red + (rr * 64 + l) * 6;
#pragma unroll
                for (int di = 0; di < 2; ++di)
#pragma unroll
                    for (int dj = 0; dj < 3; ++dj)
                        acc[di][dj] += rp[di * 3 + dj];
            }
            // S = b2 + sum(w2)
            f32x4 v0 = *(const f32x4*)(w2 + l * 8);
            f32x4 v1 = *(const f32x4*)(w2 + l * 8 + 4);
            float sv = (v0[0] + v0[1]) + (v0[2] + v0[3])
                     + (v1[0] + v1[1]) + (v1[2] + v1[3]);
#pragma unroll
            for (int off = 32; off; off >>= 1) sv += __shfl_xor(sv, off, 64);
            float Sv = sv + b2[0];

#pragma unroll
            for (int di = 0; di < 2; ++di) {
                int i = it * 16 + 2 * pi + di;
                float* op = out + (b * NN + i) * NN + jt * 24 + 3 * pj;
#pragma unroll
                for (int dj = 0; dj < 3; ++dj)
                    op[dj] = __builtin_fmaf(-2.f, acc[di][dj], Sv);
            }
        }
    }
}

// ---------------------------------------------------------------------------
extern "C" void kernel_launch(void* const* d_in, const int* in_sizes, int n_in,
                              void* d_out, int out_size, void* d_ws, size_t ws_size,
                              hipStream_t stream) {
    (void)in_sizes; (void)n_in; (void)out_size; (void)ws_size;

    const float* X  = (const float*)d_in[0];   // (32, 96, 512)
    const float* W1 = (const float*)d_in[1];   // (512, 1024)
    const float* b1 = (const float*)d_in[2];   // (512,)
    const float* W2 = (const float*)d_in[3];   // (1, 512)
    const float* b2 = (const float*)d_in[4];   // (1,)
    float* out = (float*)d_out;                // (32, 96, 96)

    char* ws = (char*)d_ws;
    _Float16* Ea = (_Float16*)(ws);                // 3,145,728 B
    _Float16* Eh = (_Float16*)(ws + 3145728);      // 3,145,728 B
    int* cnt     = (int*)(ws + 6291456);           // 8 ints (zeroed below)

    (void)hipMemsetAsync(cnt, 0, 32 * sizeof(int), stream);
    fused_pc<<<768, 256, 0, stream>>>(X, W1, b1, W2, b2, Ea, Eh, cnt, out);
}

// Round 21
// 39.622 us; speedup vs baseline: 2.1140x; 2.1140x over previous
//
#include <hip/hip_runtime.h>
#include <hip/hip_bf16.h>

#define NN 96
// tanh(x) = 1 - 2/(exp2(C*x)+1), C = 2*log2(e)
#define C_TANH 2.8853900817779268f

typedef __attribute__((ext_vector_type(4))) float        f32x4;
typedef __attribute__((ext_vector_type(2))) float        f32x2;
typedef __attribute__((ext_vector_type(8))) short        short8;
typedef __attribute__((ext_vector_type(8))) _Float16     half8;
typedef __attribute__((ext_vector_type(4))) unsigned int u32x4;

static __device__ inline unsigned int cvt_pk_bf16(float lo, float hi) {
    unsigned int r;
    asm("v_cvt_pk_bf16_f32 %0, %1, %2" : "=v"(r) : "v"(lo), "v"(hi));
    return r;
}

// ---------------------------------------------------------------------------
// K0: fp32 -> bf16 pre-convert of X and W1, PRE-SWIZZLED: within each 64B
// (4x16B-chunk) group of a row, chunk at position p holds original chunk
// p ^ (row&3). The gemm then stages rows linearly and its proven
// koffs ^ ((lr&3)<<3) fragment reads Just Work.
//   Xb[r][*]  r in [0,3072)  from X row r            (cols 0..511)
//   Wb[n][*]  n in [0,1024)  from W1 row n&511, col half (n>>9)*512
// 262144 16B-chunks total; 1024 blocks x 256 thr.
// ---------------------------------------------------------------------------
__global__ __launch_bounds__(256) void cvt_swz(const float* __restrict__ X,
                                               const float* __restrict__ W1,
                                               unsigned short* __restrict__ Xb,
                                               unsigned short* __restrict__ Wb) {
    int idx = blockIdx.x * 256 + threadIdx.x;
    const float* src;
    unsigned short* dst;
    if (idx < 196608) {
        int r = idx >> 6, c = idx & 63;
        int sc = (c & ~3) | ((c & 3) ^ (r & 3));
        src = X + r * 512 + sc * 8;
        dst = Xb + r * 512 + c * 8;
    } else {
        int i2 = idx - 196608;
        int n = i2 >> 6, c = i2 & 63;
        int sc = (c & ~3) | ((c & 3) ^ (n & 3));
        src = W1 + (n & 511) * 1024 + ((n >> 9) << 9) + sc * 8;
        dst = Wb + n * 512 + c * 8;
    }
    f32x4 f0 = *(const f32x4*)(src);
    f32x4 f1 = *(const f32x4*)(src + 4);
    u32x4 u;
    u.x = cvt_pk_bf16(f0[0], f0[1]); u.y = cvt_pk_bf16(f0[2], f0[3]);
    u.z = cvt_pk_bf16(f1[0], f1[1]); u.w = cvt_pk_bf16(f1[2], f1[3]);
    *(u32x4*)dst = u;
}

// ---------------------------------------------------------------------------
// K1 v5: bf16 MFMA GEMM + exp epilogue; inputs pre-converted & pre-swizzled.
// Staging per k-step per thread: ONE b128 global load + ONE b128 LDS write
// for A, same for B (was 4 f32x4 loads + 8 cvt_pk + 2 stores). L2 bytes
// halve (bf16). Pipeline/COMPUTE/epilogue = R8's proven structure verbatim.
// 768 blocks = 8 xcd x (6 m x 16 n); 64x64 tile; wave = 16M x 64N.
//   n < 512 : Ea[m, n]     = fp16( 2^( C * Ha ) )
//   n >= 512: Eh[m, n-512] = fp16( 2^( C * (Hb + b1) ) )
// ---------------------------------------------------------------------------
__global__ __launch_bounds__(256) void gemm_h(const unsigned short* __restrict__ Xb,
                                              const unsigned short* __restrict__ Wb,
                                              const float* __restrict__ b1,
                                              _Float16* __restrict__ Ea,
                                              _Float16* __restrict__ Eh) {
    __shared__ unsigned short As[2][2048];   // 4KB each buffer
    __shared__ unsigned short Bs[2][2048];

    int bid  = blockIdx.x;
    int xcd  = bid & 7;
    int sub  = bid >> 3;                 // 0..95
    int mloc = sub % 6;
    int nq   = sub / 6;                  // 0..15
    int mb   = (xcd * 6 + mloc) * 64;
    int nb   = nq * 64;
    int tid = threadIdx.x;
    int w   = tid >> 6;
    int l   = tid & 63;

    // staging geometry: thread -> (row 0..63, 16B chunk 0..3), linear copy
    // of the PRE-swizzled source row-slice.
    int srow = tid >> 2;
    int sg   = (tid & 3) * 8;
    const unsigned short* asrc = Xb + (mb + srow) * 512 + sg;
    const unsigned short* bsrc = Wb + (nb + srow) * 512 + sg;
    unsigned short* adst = &As[0][srow * 32 + sg];
    unsigned short* bdst = &Bs[0][srow * 32 + sg];

    u32x4 RAa, RAb, RBa, RBb;
#define LOADR(Ra, Rb, k0)                                                     \
    {                                                                         \
        Ra = *(const u32x4*)(asrc + (k0));                                    \
        Rb = *(const u32x4*)(bsrc + (k0));                                    \
    }
#define WRITER(Ra, Rb, buf)                                                   \
    {                                                                         \
        *(u32x4*)(adst + (buf) * 2048) = Ra;                                  \
        *(u32x4*)(bdst + (buf) * 2048) = Rb;                                  \
    }

    int lr    = l & 15;
    int koffs = ((l >> 4) * 8) ^ ((lr & 3) << 3);   // swizzled k-chunk
    int aoff  = (16 * w + lr) * 32 + koffs;
    int boff0 = lr * 32 + koffs;

    f32x4 acc[4] = {};

#define COMPUTE(cur)                                                          \
    {                                                                         \
        short8 afr = *(const short8*)(&As[cur][aoff]);                        \
        short8 bfr[4];                                                        \
        _Pragma("unroll")                                                     \
        for (int t = 0; t < 4; ++t)                                           \
            bfr[t] = *(const short8*)(&Bs[cur][boff0 + t * 512]);             \
        _Pragma("unroll")                                                     \
        for (int t = 0; t < 4; ++t)                                           \
            acc[t] = __builtin_amdgcn_mfma_f32_16x16x32_bf16(afr, bfr[t],     \
                                                             acc[t], 0, 0, 0);\
    }

    // pipeline: LOADR 2 ahead, WRITER 1 ahead, COMPUTE current (R8 proven)
    LOADR(RAa, RAb, 0)
    WRITER(RAa, RAb, 0)
    LOADR(RBa, RBb, 32)
    __syncthreads();
#pragma unroll 1
    for (int kk = 0; kk < 7; ++kk) {
        LOADR(RAa, RAb, (2 * kk + 2) * 32)
        COMPUTE(0)
        WRITER(RBa, RBb, 1)
        __syncthreads();
        LOADR(RBa, RBb, (2 * kk + 3) * 32)
        COMPUTE(1)
        WRITER(RAa, RAb, 0)
        __syncthreads();
    }
    COMPUTE(0)
    WRITER(RBa, RBb, 1)
    __syncthreads();
    COMPUTE(1)
#undef LOADR
#undef WRITER
#undef COMPUTE

    // epilogue: D lane l -> D[(l>>4)*4+q][l&15]
    int r0 = (l >> 4) * 4;
    bool isB = (nb >= 512);                 // uniform per block
    int colbase = nb & 511;
    _Float16* dst = isB ? Eh : Ea;
#pragma unroll
    for (int t = 0; t < 4; ++t) {
        int col = colbase + 16 * t + lr;
        float bias = isB ? b1[col] : 0.0f;
#pragma unroll
        for (int q = 0; q < 4; ++q) {
            int m = mb + 16 * w + r0 + q;
            float arg = (acc[t][q] + bias) * C_TANH;
            dst[m * 512 + col] = (_Float16)exp2f(arg);
        }
    }
}

// ---------------------------------------------------------------------------
// K2 v4 (R11-proven verbatim): out[b,i,j] = S - 2*sum_k w2[k]/(Ea*Eh+1)
//   S = b2 + sum_k w2[k], computed by wave 0 at the tail.
// Tile 16i x 16j per block, 256 thr = 4 waves; kq = wave index (SGPR) so
// w2 reads are scalar; thread = 2i x 2j x 128k; pair-rcp.
// 1152 blocks; XCD-swizzle: xcd = bid&7 owns b in [4*xcd, +4) -- the same
// rows gemm wrote on that XCD -> Ea/Eh are L2 hits.
// ---------------------------------------------------------------------------
__global__ __launch_bounds__(256) void arc_kernel(const _Float16* __restrict__ Ea,
                                                  const _Float16* __restrict__ Eh,
                                                  const float* __restrict__ w2,
                                                  const float* __restrict__ b2,
                                                  float* __restrict__ out) {
    __shared__ _Float16 a_s[16 * 512];   // 16 KB
    __shared__ _Float16 h_s[16 * 512];   // 16 KB
    __shared__ float    red[3][64][4];   // 3 KB

    int bid = blockIdx.x;                // 32 * 6 * 6 = 1152
    int xcd = bid & 7;
    int sub = bid >> 3;                  // 0..143
    int b   = xcd * 4 + sub / 36;
    int r   = sub % 36;
    int it  = r / 6;
    int jt  = r % 6;
    int tid = threadIdx.x;

    const _Float16* asrc = Ea + (b * NN + it * 16) * 512;
    const _Float16* hsrc = Eh + (b * NN + jt * 16) * 512;

#pragma unroll
    for (int p = 0; p < 4; ++p) {
        int idx = tid + p * 256;
        int row = idx >> 6, c = idx & 63;
        int cs = c ^ (row & 7);
        *(f32x4*)(a_s + row * 512 + cs * 8) = *(const f32x4*)(asrc + row * 512 + c * 8);
        *(f32x4*)(h_s + row * 512 + cs * 8) = *(const f32x4*)(hsrc + row * 512 + c * 8);
    }
    __syncthreads();

    int w  = tid >> 6;
    int kq = __builtin_amdgcn_readfirstlane(w);   // SGPR 0..3
    int l  = tid & 63;
    int pi = l >> 3;
    int pj = l & 7;
    int r0a = pi * 2, r1a = r0a + 1;
    int r0h = pj * 2, r1h = r0h + 1;

    const _Float16* a0 = a_s + r0a * 512 + kq * 128;
    const _Float16* a1 = a_s + r1a * 512 + kq * 128;
    const _Float16* h0 = h_s + r0h * 512 + kq * 128;
    const _Float16* h1 = h_s + r1h * 512 + kq * 128;
    int sa0 = r0a & 7, sa1 = r1a & 7, sh0 = r0h & 7, sh1 = r1h & 7;
    const float* wp = w2 + kq * 128;     // uniform -> s_load

    float acc00 = 0.f, acc01 = 0.f, acc10 = 0.f, acc11 = 0.f;

#define PROC(av, hv, acc)                                                     \
    {                                                                         \
        float s0 = __builtin_fmaf((float)av[0], (float)hv[0], 1.0f);          \
        float s1 = __builtin_fmaf((float)av[1], (float)hv[1], 1.0f);          \
        float s2 = __builtin_fmaf((float)av[2], (float)hv[2], 1.0f);          \
        float s3 = __builtin_fmaf((float)av[3], (float)hv[3], 1.0f);          \
        float s4 = __builtin_fmaf((float)av[4], (float)hv[4], 1.0f);          \
        float s5 = __builtin_fmaf((float)av[5], (float)hv[5], 1.0f);          \
        float s6 = __builtin_fmaf((float)av[6], (float)hv[6], 1.0f);          \
        float s7 = __builtin_fmaf((float)av[7], (float)hv[7], 1.0f);          \
        float n0 = __builtin_fmaf(wv1, s0, wv0 * s1);                         \
        float n1 = __builtin_fmaf(wv3, s2, wv2 * s3);                         \
        float n2 = __builtin_fmaf(wv5, s4, wv4 * s5);                         \
        float n3 = __builtin_fmaf(wv7, s6, wv6 * s7);                         \
        acc = __builtin_fmaf(n0, __builtin_amdgcn_rcpf(s0 * s1), acc);        \
        acc = __builtin_fmaf(n1, __builtin_amdgcn_rcpf(s2 * s3), acc);        \
        acc = __builtin_fmaf(n2, __builtin_amdgcn_rcpf(s4 * s5), acc);        \
        acc = __builtin_fmaf(n3, __builtin_amdgcn_rcpf(s6 * s7), acc);        \
    }

#pragma unroll 4
    for (int c = 0; c < 16; ++c) {
        half8 av0 = *(const half8*)(a0 + ((c ^ sa0) << 3));
        half8 av1 = *(const half8*)(a1 + ((c ^ sa1) << 3));
        half8 hv0 = *(const half8*)(h0 + ((c ^ sh0) << 3));
        half8 hv1 = *(const half8*)(h1 + ((c ^ sh1) << 3));
        f32x4 wlo = *(const f32x4*)(wp + c * 8);
        f32x4 whi = *(const f32x4*)(wp + c * 8 + 4);
        float wv0 = wlo[0], wv1 = wlo[1], wv2 = wlo[2], wv3 = wlo[3];
        float wv4 = whi[0], wv5 = whi[1], wv6 = whi[2], wv7 = whi[3];
        PROC(av0, hv0, acc00)
        PROC(av0, hv1, acc01)
        PROC(av1, hv0, acc10)
        PROC(av1, hv1, acc11)
    }
#undef PROC

    if (w != 0) {
        f32x4 v = {acc00, acc01, acc10, acc11};
        *(f32x4*)(&red[w - 1][l][0]) = v;
    }
    __syncthreads();

    if (w == 0) {
#pragma unroll
        for (int rr = 0; rr < 3; ++rr) {
            f32x4 v = *(const f32x4*)(&red[rr][l][0]);
            acc00 += v[0]; acc01 += v[1]; acc10 += v[2]; acc11 += v[3];
        }
        f32x4 v0 = *(const f32x4*)(w2 + l * 8);
        f32x4 v1 = *(const f32x4*)(w2 + l * 8 + 4);
        float sv = (v0[0] + v0[1]) + (v0[2] + v0[3])
                 + (v1[0] + v1[1]) + (v1[2] + v1[3]);
#pragma unroll
        for (int off = 32; off; off >>= 1) sv += __shfl_xor(sv, off, 64);
        float Sv = sv + b2[0];

        int i0 = it * 16 + r0a;
        int j0 = jt * 16 + r0h;
        f32x2 o0 = {__builtin_fmaf(-2.f, acc00, Sv), __builtin_fmaf(-2.f, acc01, Sv)};
        f32x2 o1 = {__builtin_fmaf(-2.f, acc10, Sv), __builtin_fmaf(-2.f, acc11, Sv)};
        *(f32x2*)(out + (b * NN + i0) * NN + j0)     = o0;
        *(f32x2*)(out + (b * NN + i0 + 1) * NN + j0) = o1;
    }
}

// ---------------------------------------------------------------------------
extern "C" void kernel_launch(void* const* d_in, const int* in_sizes, int n_in,
                              void* d_out, int out_size, void* d_ws, size_t ws_size,
                              hipStream_t stream) {
    (void)in_sizes; (void)n_in; (void)out_size; (void)ws_size;

    const float* X  = (const float*)d_in[0];   // (32, 96, 512)
    const float* W1 = (const float*)d_in[1];   // (512, 1024)
    const float* b1 = (const float*)d_in[2];   // (512,)
    const float* W2 = (const float*)d_in[3];   // (1, 512)
    const float* b2 = (const float*)d_in[4];   // (1,)
    float* out = (float*)d_out;                // (32, 96, 96)

    char* ws = (char*)d_ws;
    unsigned short* Xb = (unsigned short*)(ws);              // 3,145,728 B
    unsigned short* Wb = (unsigned short*)(ws + 3145728);    // 1,048,576 B
    _Float16* Ea = (_Float16*)(ws + 4194304);                // 3,145,728 B
    _Float16* Eh = (_Float16*)(ws + 7340032);                // 3,145,728 B

    cvt_swz<<<1024, 256, 0, stream>>>(X, W1, Xb, Wb);
    gemm_h<<<768, 256, 0, stream>>>(Xb, Wb, b1, Ea, Eh);
    arc_kernel<<<1152, 256, 0, stream>>>(Ea, Eh, W2, b2, out);
}